// Round 6
// baseline (180.714 us; speedup 1.0000x reference)
//
#include <hip/hip_runtime.h>
#include <cstdint>
#include <cstddef>

// Problem constants (from reference setup_inputs)
#define BB   8
#define NN   2048
#define DD   16
#define HHH  64
#define KK   32
#define CAP  96          // max within-R candidates kept (mean ~36, Poisson tail safe)
#define FCAP 48          // max fwd neighbors kept (<=32 barring exact d2 ties)
#define DT_C 0.01f
#define R2_C (0.08f * 0.08f)
#define CEXP (-2.885390081777927f)   // -2*log2(e):  exp(-2|z|) = exp2(CEXP*|z|)

#define WPB1  16                // waves per block, k_neighbors
#define BLK1  (WPB1 * 64)
#define WPB2  8                 // waves per block, k_grad
#define BLK2  (WPB2 * 64)

// Bit-deterministic distance (no fma contraction) — k_grad consumes k1's stored
// d2 directly, so determinism only needs to hold within k_neighbors now.
__device__ __forceinline__ float dist2(float px, float py, float qx, float qy) {
    float dx = __fsub_rn(px, qx);
    float dy = __fsub_rn(py, qy);
    return __fadd_rn(__fmul_rn(dx, dx), __fmul_rn(dy, dy));
}

__device__ __forceinline__ int mbcnt64(unsigned long long m) {
    return (int)__builtin_amdgcn_mbcnt_hi(
        (unsigned)(m >> 32), __builtin_amdgcn_mbcnt_lo((unsigned)m, 0u));
}

// XCD-aware swizzle: batch = blockIdx & 7 so each XCD's L2 caches exactly one
// batch's cut/AD/cand slices. Heuristic only — correctness-free.
__device__ __forceinline__ int swizzled_particle(int blk, int wpb, int w, int& bbase) {
    int vb = blk & 7, vi = blk >> 3;
    bbase = vb << 11;
    return bbase + vi * wpb + w;
}

// Kernel 1 per step, one wave per particle p:
//  - A_p[h] = x_p @ W1[:16], D_p[h] = x_p @ W1[16:]  -> separate A/D planes
//  - collect candidates {j : d2 < R^2, j != p} via ballot+mbcnt compaction
//  - cutoff_p = 32nd smallest candidate d2 (bitonic sort; LDS rank-select if cnt>64)
//  - emit candList {d2,j} (for k_grad's rev test) + pre-compacted fwd u16 list
//  - cntArr[p] = cnt | (fwd_count << 16)
template <bool FIRST>
__global__ __launch_bounds__(BLK1) void k_neighbors(
    const float* __restrict__ x, const float* __restrict__ pos,
    const float* __restrict__ W1,
    float2* __restrict__ candList, unsigned short* __restrict__ fwdList,
    int* __restrict__ cntArr, float* __restrict__ cutArr,
    float* __restrict__ Aplane, float* __restrict__ Dplane) {
    __shared__ float sPos[2 * NN];          // 16 KB
    __shared__ float sW1[2 * DD * HHH];     // 8 KB
    __shared__ float2 sDJ[WPB1][CAP];       // 12 KB packed {d2, j-bits}

    int tid = threadIdx.x;
    int w = tid >> 6, lane = tid & 63;
    int bbase;
    int p = swizzled_particle(blockIdx.x, WPB1, w, bbase);
    int pl = p & (NN - 1);

    float2* sPos2w = (float2*)sPos;
    if (FIRST) {
        for (int t = tid; t < NN; t += BLK1)
            sPos2w[t] = *(const float2*)(x + (size_t)(bbase + t) * DD);
    } else {
        for (int t = tid; t < 2 * NN; t += BLK1) sPos[t] = pos[bbase * 2 + t];
    }
    for (int t = tid; t < 2 * DD * HHH; t += BLK1) sW1[t] = W1[t];
    __syncthreads();

    // ---- A/D precompute (lane = h), split-plane store ----
    float xv = (lane < DD) ? x[(size_t)p * DD + lane] : 0.f;
    float A = 0.f, Dv = 0.f;
#pragma unroll
    for (int f = 0; f < DD; f++) {
        float xf = __shfl(xv, f);
        A  = fmaf(xf, sW1[f * HHH + lane], A);
        Dv = fmaf(xf, sW1[(DD + f) * HHH + lane], Dv);
    }
    Aplane[((size_t)p << 6) + lane] = A;
    Dplane[((size_t)p << 6) + lane] = Dv;

    // ---- candidate collection: 4-wide chunking for LDS-load ILP ----
    float px = sPos[2 * pl], py = sPos[2 * pl + 1];
    const float2* sPos2 = (const float2*)sPos;
    int cnt = 0;
    for (int c0 = 0; c0 < NN; c0 += 256) {
        float2 q[4];
#pragma unroll
        for (int u = 0; u < 4; ++u) q[u] = sPos2[c0 + (u << 6) + lane];
#pragma unroll
        for (int u = 0; u < 4; ++u) {
            int j = c0 + (u << 6) + lane;
            float d2 = dist2(px, py, q[u].x, q[u].y);
            bool hit = (d2 < R2_C) && (j != pl);
            unsigned long long m = __ballot(hit);
            int idx = cnt + mbcnt64(m & ((1ull << lane) - 1ull));
            if (hit && idx < CAP)
                sDJ[w][idx] = make_float2(d2, __uint_as_float((unsigned)j));
            cnt += (int)__popcll(m);
        }
    }
    if (cnt > CAP) cnt = CAP;
    __threadfence_block();   // wave-local LDS RAW drain

    // ---- cutoff = K-th smallest candidate d2 (value-exact selection) ----
    float cutoff = R2_C;
    if (cnt > KK) {
        const float INF = 1e30f;
        if (cnt <= 64) {
            float v = (lane < cnt) ? sDJ[w][lane].x : INF;
#pragma unroll
            for (int k = 2; k <= 64; k <<= 1) {
#pragma unroll
                for (int j = k >> 1; j > 0; j >>= 1) {
                    float pv = __shfl_xor(v, j);
                    bool up = ((lane & k) == 0);
                    bool takeMin = (((lane & j) == 0) == up);
                    v = takeMin ? fminf(v, pv) : fmaxf(v, pv);
                }
            }
            cutoff = __shfl(v, KK - 1);   // ascending sort -> 32nd smallest
        } else {                          // cnt in (64,96]: ~never, kept for correctness
            float e0 = (lane < cnt) ? sDJ[w][lane].x : INF;
            float e1 = (lane + 64 < cnt) ? sDJ[w][lane + 64].x : INF;
            int r0 = 0, q0 = 0, r1 = 0, q1 = 0;
            for (int k = 0; k < cnt; k++) {
                float val = sDJ[w][k].x;
                r0 += (val < e0); q0 += (val == e0);
                r1 += (val < e1); q1 += (val == e1);
            }
            bool c0 = (r0 <= KK - 1) && (r0 + q0 > KK - 1);
            bool c1 = (r1 <= KK - 1) && (r1 + q1 > KK - 1);
            float cand = c0 ? e0 : (c1 ? e1 : INF);
#pragma unroll
            for (int off = 32; off; off >>= 1) cand = fminf(cand, __shfl_xor(cand, off));
            cutoff = cand;
        }
    }

    // ---- emit candList {d2,j} and fwd list compacted in candidate order ----
    int mf = 0;
    for (int c0 = 0; c0 < cnt; c0 += 64) {
        int c = c0 + lane;
        bool act = c < cnt;
        float2 e = sDJ[w][act ? c : 0];
        if (act) candList[(size_t)p * CAP + c] = e;
        bool fwd = act && (e.x <= cutoff);
        unsigned long long mF = __ballot(fwd);
        int iF = mf + mbcnt64(mF & ((1ull << lane) - 1ull));
        if (fwd && iF < FCAP)
            fwdList[(size_t)p * FCAP + iF] = (unsigned short)__float_as_uint(e.y);
        mf += (int)__popcll(mF);
    }
    if (mf > FCAP) mf = FCAP;
    if (lane == 0) { cutArr[p] = cutoff; cntArr[p] = cnt | (mf << 16); }
}

// Kernel 2 per step, one wave per particle p (lane = h):
//  prepass: coalesced candList {d2,j} load + cut[j] gather -> rev ballot-compact;
//           fwd list staged by one guarded coalesced copy (no recompute at all)
//  main:    T1 += sech2/4((Ap+b1)+D_j); T2 += sech2/4((Dp+b1)+A_j); S = 4v*T
//  epilogue: grad_p = W1_top @ S1 + W1_bot @ S2; x_next = x - DT*grad
__global__ __launch_bounds__(BLK2) void k_grad(
    const float* __restrict__ x,
    const float* __restrict__ cutArr, const int* __restrict__ cntArr,
    const float2* __restrict__ candList, const unsigned short* __restrict__ fwdList,
    const float* __restrict__ Aplane, const float* __restrict__ Dplane,
    const float* __restrict__ W1, const float* __restrict__ b1,
    const float* __restrict__ W2, const float* __restrict__ Wout,
    float* __restrict__ xOut, float* __restrict__ posOut) {
    __shared__ float sW1t[HHH * 33];                       // 8.25 KB
    __shared__ alignas(16) unsigned short sFwd[WPB2][FCAP];// 768 B
    __shared__ alignas(16) unsigned short sRev[WPB2][CAP]; // 1.5 KB
    __shared__ float sS[WPB2][128];                        // 4 KB
    __shared__ float sV[HHH];                              // (~14.8 KB total)

    int tid = threadIdx.x;
    int w = tid >> 6, h = tid & 63;
    int bbase;
    int p = swizzled_particle(blockIdx.x, WPB2, w, bbase);

    for (int t = tid; t < 2 * DD * HHH; t += BLK2) {
        int f = t >> 6, hh = t & 63;
        sW1t[hh * 33 + f] = W1[t];            // pad 33: conflict-free write & read
    }
    if (tid < HHH) {                          // v = W2 @ Wout
        float acc = 0.f;
        for (int c = 0; c < 32; c++) acc = fmaf(W2[tid * 32 + c], Wout[c], acc);
        sV[tid] = acc;
    }
    __syncthreads();                          // the only block barrier

    float b1h = b1[h];
    float Apb = Aplane[((size_t)p << 6) + h] + b1h;
    float Dpb = Dplane[((size_t)p << 6) + h] + b1h;
    float vh4 = 4.f * sV[h];
    int packed = cntArr[p];
    int cnt = packed & 0xffff;
    int mf = packed >> 16;

    // stage fwd list: one guarded coalesced copy (k1 already compacted it)
    if (h < mf) sFwd[w][h] = fwdList[(size_t)p * FCAP + h];

    // ---- rev prepass: stored d2 vs cut[j] gather, ballot-compact ----
    int mr = 0;
    for (int c0 = 0; c0 < cnt; c0 += 64) {
        int c = c0 + h;
        bool act = c < cnt;
        float2 e = candList[(size_t)p * CAP + (act ? c : 0)];
        unsigned jl = __float_as_uint(e.y) & (NN - 1);
        bool rev = act && (e.x <= cutArr[bbase + jl]);
        unsigned long long mR = __ballot(rev);
        int iR = mr + mbcnt64(mR & ((1ull << h) - 1ull));
        if (rev) sRev[w][iR] = (unsigned short)jl;
        mr += (int)__popcll(mR);
    }
    __threadfence_block();

    // ---- main loops: branch-free, 16-deep gather batching, scalar-decoded ----
    const float* baseD = Dplane + ((size_t)bbase << 6);
    const float* baseA = Aplane + ((size_t)bbase << 6);
    float T1 = 0.f, T2 = 0.f;

    auto s2core = [&](float z) {
        float a = __builtin_amdgcn_exp2f(CEXP * fabsf(z));
        float bb = 1.f + a;
        return a * __builtin_amdgcn_rcpf(bb * bb);
    };

#define UNPACK8(Q0, Q1, U)                                            \
    unsigned U[8];                                                    \
    U[0] = (unsigned)__builtin_amdgcn_readfirstlane(Q0.x);            \
    U[1] = (unsigned)__builtin_amdgcn_readfirstlane(Q0.y);            \
    U[2] = (unsigned)__builtin_amdgcn_readfirstlane(Q0.z);            \
    U[3] = (unsigned)__builtin_amdgcn_readfirstlane(Q0.w);            \
    U[4] = (unsigned)__builtin_amdgcn_readfirstlane(Q1.x);            \
    U[5] = (unsigned)__builtin_amdgcn_readfirstlane(Q1.y);            \
    U[6] = (unsigned)__builtin_amdgcn_readfirstlane(Q1.z);            \
    U[7] = (unsigned)__builtin_amdgcn_readfirstlane(Q1.w);

    {   // fwd stream: T1 += s2(Apb + D_j)
        const unsigned short* L = sFwd[w];
        int c = 0;
        for (; c + 16 <= mf; c += 16) {
            int4 q0 = *(const int4*)(L + c);
            int4 q1 = *(const int4*)(L + c + 8);
            UNPACK8(q0, q1, u)
            float d[16];
#pragma unroll
            for (int k = 0; k < 8; ++k) {     // 16 independent gathers in flight
                d[2 * k]     = baseD[((size_t)(u[k] & 0xffffu) << 6) + h];
                d[2 * k + 1] = baseD[((size_t)(u[k] >> 16) << 6) + h];
            }
#pragma unroll
            for (int k = 0; k < 16; ++k) T1 += s2core(Apb + d[k]);
        }
        for (; c + 8 <= mf; c += 8) {
            int4 q0 = *(const int4*)(L + c);
            int4 q1 = q0;
            UNPACK8(q0, q1, u)
            float d[8];
#pragma unroll
            for (int k = 0; k < 4; ++k) {
                d[2 * k]     = baseD[((size_t)(u[k] & 0xffffu) << 6) + h];
                d[2 * k + 1] = baseD[((size_t)(u[k] >> 16) << 6) + h];
            }
#pragma unroll
            for (int k = 0; k < 8; ++k) T1 += s2core(Apb + d[k]);
        }
        for (; c < mf; ++c) {
            unsigned jl = (unsigned)__builtin_amdgcn_readfirstlane((int)L[c]);
            T1 += s2core(Apb + baseD[((size_t)jl << 6) + h]);
        }
    }
    {   // rev stream: T2 += s2(Dpb + A_j)
        const unsigned short* L = sRev[w];
        int c = 0;
        for (; c + 16 <= mr; c += 16) {
            int4 q0 = *(const int4*)(L + c);
            int4 q1 = *(const int4*)(L + c + 8);
            UNPACK8(q0, q1, u)
            float d[16];
#pragma unroll
            for (int k = 0; k < 8; ++k) {
                d[2 * k]     = baseA[((size_t)(u[k] & 0xffffu) << 6) + h];
                d[2 * k + 1] = baseA[((size_t)(u[k] >> 16) << 6) + h];
            }
#pragma unroll
            for (int k = 0; k < 16; ++k) T2 += s2core(Dpb + d[k]);
        }
        for (; c + 8 <= mr; c += 8) {
            int4 q0 = *(const int4*)(L + c);
            int4 q1 = q0;
            UNPACK8(q0, q1, u)
            float d[8];
#pragma unroll
            for (int k = 0; k < 4; ++k) {
                d[2 * k]     = baseA[((size_t)(u[k] & 0xffffu) << 6) + h];
                d[2 * k + 1] = baseA[((size_t)(u[k] >> 16) << 6) + h];
            }
#pragma unroll
            for (int k = 0; k < 8; ++k) T2 += s2core(Dpb + d[k]);
        }
        for (; c < mr; ++c) {
            unsigned jl = (unsigned)__builtin_amdgcn_readfirstlane((int)L[c]);
            T2 += s2core(Dpb + baseA[((size_t)jl << 6) + h]);
        }
    }
#undef UNPACK8

    sS[w][h] = vh4 * T1;
    sS[w][64 + h] = vh4 * T2;
    __threadfence_block();                    // wave-local: no block barrier needed

    float g = 0.f;
    if (h < 32) {                             // l<16: W1_top@S1 ; 16<=l<32: W1_bot@S2
        const float* Sv = &sS[w][(h < 16) ? 0 : 64];
        float acc = 0.f;
        for (int hh = 0; hh < 64; hh++) acc = fmaf(sW1t[hh * 33 + h], Sv[hh], acc);
        g = acc;
    }
    float g2 = __shfl(g, (h + 16) & 63);
    if (h < DD) {
        float xn = x[(size_t)p * DD + h] - DT_C * (g + g2);
        xOut[(size_t)p * DD + h] = xn;
        if (h < 2) posOut[p * 2 + h] = xn;
    }
}

extern "C" void kernel_launch(void* const* d_in, const int* in_sizes, int n_in,
                              void* d_out, int out_size, void* d_ws, size_t ws_size,
                              hipStream_t stream) {
    const float* x0   = (const float*)d_in[0];
    const float* W1   = (const float*)d_in[1];
    const float* b1   = (const float*)d_in[2];
    const float* W2   = (const float*)d_in[3];
    const float* Wout = (const float*)d_in[5];
    float* out = (float*)d_out;

    // workspace layout (floats); total ~23 MB
    float* ws   = (float*)d_ws;
    float* posA = ws;                        // 32768 (dead sink for last step)
    float* posB = posA + 32768;              // 32768
    float* x1   = posB + 32768;              // 262144
    float* Apl  = x1 + 262144;               // 16384*64 (4 MB)
    float* Dpl  = Apl + 16384 * 64;          // 16384*64 (4 MB)
    float* cut  = Dpl + 16384 * 64;          // 16384
    int*   cnt  = (int*)(cut + 16384);       // 16384
    float2* cand = (float2*)(cnt + 16384);   // 16384*96 float2 (12.6 MB), 8B-aligned
    unsigned short* fwd = (unsigned short*)(cand + (size_t)16384 * CAP);  // 16384*48

    const int NB1 = (BB * NN) / WPB1;        // 1024 blocks x 1024 thr
    const int NB2 = (BB * NN) / WPB2;        // 2048 blocks x 512 thr

    // step 0: x0 -> x1 (positions read straight from x0)
    k_neighbors<true><<<NB1, BLK1, 0, stream>>>(x0, nullptr, W1, cand, fwd, cnt, cut,
                                                Apl, Dpl);
    k_grad<<<NB2, BLK2, 0, stream>>>(x0, cut, cnt, cand, fwd, Apl, Dpl,
                                     W1, b1, W2, Wout, x1, posB);
    // step 1: x1 -> out
    k_neighbors<false><<<NB1, BLK1, 0, stream>>>(x1, posB, W1, cand, fwd, cnt, cut,
                                                 Apl, Dpl);
    k_grad<<<NB2, BLK2, 0, stream>>>(x1, cut, cnt, cand, fwd, Apl, Dpl,
                                     W1, b1, W2, Wout, out, posA);
}

// Round 7
// 169.835 us; speedup vs baseline: 1.0641x; 1.0641x over previous
//
#include <hip/hip_runtime.h>
#include <cstdint>
#include <cstddef>

// Problem constants (from reference setup_inputs)
#define BB   8
#define NN   2048
#define DD   16
#define HHH  64
#define KK   32
#define CAP  96          // max within-R hits kept incl self (mean ~37, Poisson tail safe)
#define FCAP 48          // max fwd neighbors kept (<=32 barring exact d2 ties)
#define DT_C 0.01f
#define R2_C (0.08f * 0.08f)
#define CEXP (-2.885390081777927f)   // -2*log2(e):  exp(-2|z|) = exp2(CEXP*|z|)

#define BANDS    18
#define BAND_OFF 0.72f
#define BAND_INV 12.5f   // 1/0.08; bands cover y in [-0.72,0.72], clamped at edges

#define WPB   8                 // waves per block (1 particle per wave)
#define BLOCK (WPB * 64)

// Same rounding as the reference's sum-of-squares (sub,sub,mul,mul,add; no fma).
__device__ __forceinline__ float dist2(float px, float py, float qx, float qy) {
    float dx = __fsub_rn(px, qx);
    float dy = __fsub_rn(py, qy);
    return __fadd_rn(__fmul_rn(dx, dx), __fmul_rn(dy, dy));
}

// v_mbcnt_lo/hi natively count set bits among lanes BELOW the caller: prefix count.
__device__ __forceinline__ int prefix_cnt(unsigned long long m) {
    return (int)__builtin_amdgcn_mbcnt_hi(
        (unsigned)(m >> 32), __builtin_amdgcn_mbcnt_lo((unsigned)m, 0u));
}

// XCD-aware swizzle: batch = blockIdx & 7 so each XCD's L2 caches one batch's
// sortedPos/cut/AD/cand slices. Heuristic only — correctness-free.
__device__ __forceinline__ int swizzled_particle(int blk, int w, int& bbase) {
    int vb = blk & 7, vi = blk >> 3;
    bbase = vb << 11;
    return bbase + vi * WPB + w;
}

// Per step, one block per batch: counting-sort particles into 18 y-bands of
// width R. sortedPos entries are verbatim copies -> d2 bits unchanged.
template <bool FIRST>
__global__ __launch_bounds__(1024) void k_bin(
    const float* __restrict__ x, const float* __restrict__ pos,
    float2* __restrict__ sortedPos, unsigned short* __restrict__ sortedIdx,
    int* __restrict__ bandStart) {
    __shared__ int hist[BANDS], base[BANDS + 1], cursor[BANDS];
    int bat = blockIdx.x;
    int bbase = bat << 11;
    int tid = threadIdx.x;
    if (tid < BANDS) hist[tid] = 0;
    __syncthreads();
    float2 q[2]; int bd[2];
#pragma unroll
    for (int u = 0; u < 2; ++u) {
        int i = tid + (u << 10);
        float2 qq;
        if (FIRST) qq = *(const float2*)(x + (size_t)(bbase + i) * DD);
        else       qq = *(const float2*)(pos + (size_t)(bbase + i) * 2);
        q[u] = qq;
        int band = (int)((qq.y + BAND_OFF) * BAND_INV);
        band = band < 0 ? 0 : (band > BANDS - 1 ? BANDS - 1 : band);
        bd[u] = band;
        atomicAdd(&hist[band], 1);
    }
    __syncthreads();
    if (tid == 0) {
        int acc = 0;
        for (int k = 0; k < BANDS; ++k) { base[k] = acc; cursor[k] = acc; acc += hist[k]; }
        base[BANDS] = acc;
    }
    __syncthreads();
    if (tid <= BANDS) bandStart[bat * 32 + tid] = base[tid];
#pragma unroll
    for (int u = 0; u < 2; ++u) {
        int i = tid + (u << 10);
        int dst = atomicAdd(&cursor[bd[u]], 1);
        sortedPos[bbase + dst] = q[u];
        sortedIdx[bbase + dst] = (unsigned short)i;   // batch-local index
    }
}

// Kernel 1 per step, one wave per particle p:
//  - A_p[h] = x_p @ W1[:16], D_p[h] = x_p @ W1[16:]  -> separate A/D planes
//  - scan only y-bands b(p)-1..b(p)+1 of the sorted array (~410 candidates);
//    self included (d2=0 exactly) -> cutoff rank KK (0-based) instead of KK-1
//  - emit candList {d2, orig j} + pre-compacted fwd u16 list (self dropped)
__global__ __launch_bounds__(BLOCK) void k_neighbors(
    const float* __restrict__ x,
    const float2* __restrict__ sortedPos, const unsigned short* __restrict__ sortedIdx,
    const int* __restrict__ bandStart, const float* __restrict__ W1,
    float2* __restrict__ candList, unsigned short* __restrict__ fwdList,
    int* __restrict__ cntArr, float* __restrict__ cutArr,
    float* __restrict__ Aplane, float* __restrict__ Dplane) {
    __shared__ float sW1[2 * DD * HHH];     // 8 KB
    __shared__ float2 sDJ[WPB][CAP];        // 6 KB packed {d2, sorted-j bits}

    int tid = threadIdx.x;
    int w = tid >> 6, lane = tid & 63;
    int bbase;
    int p = swizzled_particle(blockIdx.x, w, bbase);
    int pl = p & (NN - 1);
    int bat = bbase >> 11;

    for (int t = tid; t < 2 * DD * HHH; t += BLOCK) sW1[t] = W1[t];
    __syncthreads();                        // the only block barrier

    // ---- A/D precompute (lane = h); own position for free via shfl ----
    float xv = (lane < DD) ? x[(size_t)p * DD + lane] : 0.f;
    float px = __shfl(xv, 0), py = __shfl(xv, 1);
    float A = 0.f, Dv = 0.f;
#pragma unroll
    for (int f = 0; f < DD; f++) {
        float xf = __shfl(xv, f);
        A  = fmaf(xf, sW1[f * HHH + lane], A);
        Dv = fmaf(xf, sW1[(DD + f) * HHH + lane], Dv);
    }
    Aplane[((size_t)p << 6) + lane] = A;
    Dplane[((size_t)p << 6) + lane] = Dv;

    // ---- banded candidate scan (self included: d2=0 < R^2 always hits) ----
    int bb = (int)((py + BAND_OFF) * BAND_INV);
    bb = bb < 0 ? 0 : (bb > BANDS - 1 ? BANDS - 1 : bb);
    int lo = bandStart[bat * 32 + (bb > 0 ? bb - 1 : 0)];
    int hi = bandStart[bat * 32 + (bb < BANDS - 1 ? bb + 2 : BANDS)];

    int cnt = 0;
    for (int c0 = lo; c0 < hi; c0 += 64) {
        int j = c0 + lane;
        float2 q = (j < hi) ? sortedPos[bbase + j] : make_float2(1e30f, 1e30f);
        float d2 = dist2(px, py, q.x, q.y);
        bool hit = (j < hi) && (d2 < R2_C);
        unsigned long long m = __ballot(hit);
        int idx = cnt + prefix_cnt(m);
        if (hit && idx < CAP)
            sDJ[w][idx] = make_float2(d2, __uint_as_float((unsigned)j));
        cnt += (int)__popcll(m);
    }
    if (cnt > CAP) cnt = CAP;
    __threadfence_block();   // wave-local LDS RAW drain

    // ---- cutoff = (KK)th value 0-based incl self == KK-th smallest among others ----
    float cutoff = R2_C;
    if (cnt > KK + 1) {
        const float INF = 1e30f;
        if (cnt <= 64) {
            float v = (lane < cnt) ? sDJ[w][lane].x : INF;
#pragma unroll
            for (int k = 2; k <= 64; k <<= 1) {
#pragma unroll
                for (int j = k >> 1; j > 0; j >>= 1) {
                    float pv = __shfl_xor(v, j);
                    bool up = ((lane & k) == 0);
                    bool takeMin = (((lane & j) == 0) == up);
                    v = takeMin ? fminf(v, pv) : fmaxf(v, pv);
                }
            }
            cutoff = __shfl(v, KK);       // ascending; rank shifted by self
        } else {                          // cnt in (64,96]: ~never, kept for correctness
            float e0 = (lane < cnt) ? sDJ[w][lane].x : INF;
            float e1 = (lane + 64 < cnt) ? sDJ[w][lane + 64].x : INF;
            int r0 = 0, q0 = 0, r1 = 0, q1 = 0;
            for (int k = 0; k < cnt; k++) {
                float val = sDJ[w][k].x;
                r0 += (val < e0); q0 += (val == e0);
                r1 += (val < e1); q1 += (val == e1);
            }
            bool c0 = (r0 <= KK) && (r0 + q0 > KK);
            bool c1 = (r1 <= KK) && (r1 + q1 > KK);
            float cand = c0 ? e0 : (c1 ? e1 : INF);
#pragma unroll
            for (int off = 32; off; off >>= 1) cand = fminf(cand, __shfl_xor(cand, off));
            cutoff = cand;
        }
    }

    // ---- emission: map sorted->orig, drop self, compact cand + fwd lists ----
    int me = 0, mf = 0;
    for (int c0 = 0; c0 < cnt; c0 += 64) {
        int c = c0 + lane;
        bool act = c < cnt;
        float2 e = sDJ[w][act ? c : 0];
        unsigned js = __float_as_uint(e.y);
        int jo = act ? (int)sortedIdx[bbase + js] : pl;
        bool keep = act && (jo != pl);
        unsigned long long mK = __ballot(keep);
        int ie = me + prefix_cnt(mK);
        if (keep)
            candList[(size_t)p * CAP + ie] = make_float2(e.x, __uint_as_float((unsigned)jo));
        me += (int)__popcll(mK);
        bool fw = keep && (e.x <= cutoff);
        unsigned long long mF = __ballot(fw);
        int iF = mf + prefix_cnt(mF);
        if (fw && iF < FCAP) fwdList[(size_t)p * FCAP + iF] = (unsigned short)jo;
        mf += (int)__popcll(mF);
    }
    if (mf > FCAP) mf = FCAP;
    if (lane == 0) { cutArr[p] = cutoff; cntArr[p] = me | (mf << 16); }
}

// Kernel 2 per step (unchanged from round 6), one wave per particle p (lane = h).
__global__ __launch_bounds__(BLOCK) void k_grad(
    const float* __restrict__ x,
    const float* __restrict__ cutArr, const int* __restrict__ cntArr,
    const float2* __restrict__ candList, const unsigned short* __restrict__ fwdList,
    const float* __restrict__ Aplane, const float* __restrict__ Dplane,
    const float* __restrict__ W1, const float* __restrict__ b1,
    const float* __restrict__ W2, const float* __restrict__ Wout,
    float* __restrict__ xOut, float* __restrict__ posOut) {
    __shared__ float sW1t[HHH * 33];                       // 8.25 KB
    __shared__ alignas(16) unsigned short sFwd[WPB][FCAP]; // 768 B
    __shared__ alignas(16) unsigned short sRev[WPB][CAP];  // 1.5 KB
    __shared__ float sS[WPB][128];                         // 4 KB
    __shared__ float sV[HHH];                              // (~14.8 KB total)

    int tid = threadIdx.x;
    int w = tid >> 6, h = tid & 63;
    int bbase;
    int p = swizzled_particle(blockIdx.x, w, bbase);

    for (int t = tid; t < 2 * DD * HHH; t += BLOCK) {
        int f = t >> 6, hh = t & 63;
        sW1t[hh * 33 + f] = W1[t];            // pad 33: conflict-free write & read
    }
    if (tid < HHH) {                          // v = W2 @ Wout
        float acc = 0.f;
        for (int c = 0; c < 32; c++) acc = fmaf(W2[tid * 32 + c], Wout[c], acc);
        sV[tid] = acc;
    }
    __syncthreads();                          // the only block barrier

    float b1h = b1[h];
    float Apb = Aplane[((size_t)p << 6) + h] + b1h;
    float Dpb = Dplane[((size_t)p << 6) + h] + b1h;
    float vh4 = 4.f * sV[h];
    int packed = cntArr[p];
    int cnt = packed & 0xffff;
    int mf = packed >> 16;

    // stage fwd list: one guarded coalesced copy (k1 already compacted it)
    if (h < mf) sFwd[w][h] = fwdList[(size_t)p * FCAP + h];

    // ---- rev prepass: stored d2 vs cut[j] gather, ballot-compact ----
    int mr = 0;
    for (int c0 = 0; c0 < cnt; c0 += 64) {
        int c = c0 + h;
        bool act = c < cnt;
        float2 e = candList[(size_t)p * CAP + (act ? c : 0)];
        unsigned jl = __float_as_uint(e.y) & (NN - 1);
        bool rev = act && (e.x <= cutArr[bbase + jl]);
        unsigned long long mR = __ballot(rev);
        int iR = mr + prefix_cnt(mR);
        if (rev) sRev[w][iR] = (unsigned short)jl;
        mr += (int)__popcll(mR);
    }
    __threadfence_block();

    // ---- main loops: branch-free, 16-deep gather batching, scalar-decoded ----
    const float* baseD = Dplane + ((size_t)bbase << 6);
    const float* baseA = Aplane + ((size_t)bbase << 6);
    float T1 = 0.f, T2 = 0.f;

    auto s2core = [&](float z) {
        float a = __builtin_amdgcn_exp2f(CEXP * fabsf(z));
        float bb = 1.f + a;
        return a * __builtin_amdgcn_rcpf(bb * bb);
    };

#define UNPACK8(Q0, Q1, U)                                            \
    unsigned U[8];                                                    \
    U[0] = (unsigned)__builtin_amdgcn_readfirstlane(Q0.x);            \
    U[1] = (unsigned)__builtin_amdgcn_readfirstlane(Q0.y);            \
    U[2] = (unsigned)__builtin_amdgcn_readfirstlane(Q0.z);            \
    U[3] = (unsigned)__builtin_amdgcn_readfirstlane(Q0.w);            \
    U[4] = (unsigned)__builtin_amdgcn_readfirstlane(Q1.x);            \
    U[5] = (unsigned)__builtin_amdgcn_readfirstlane(Q1.y);            \
    U[6] = (unsigned)__builtin_amdgcn_readfirstlane(Q1.z);            \
    U[7] = (unsigned)__builtin_amdgcn_readfirstlane(Q1.w);

    {   // fwd stream: T1 += s2(Apb + D_j)
        const unsigned short* L = sFwd[w];
        int c = 0;
        for (; c + 16 <= mf; c += 16) {
            int4 q0 = *(const int4*)(L + c);
            int4 q1 = *(const int4*)(L + c + 8);
            UNPACK8(q0, q1, u)
            float d[16];
#pragma unroll
            for (int k = 0; k < 8; ++k) {     // 16 independent gathers in flight
                d[2 * k]     = baseD[((size_t)(u[k] & 0xffffu) << 6) + h];
                d[2 * k + 1] = baseD[((size_t)(u[k] >> 16) << 6) + h];
            }
#pragma unroll
            for (int k = 0; k < 16; ++k) T1 += s2core(Apb + d[k]);
        }
        for (; c + 8 <= mf; c += 8) {
            int4 q0 = *(const int4*)(L + c);
            int4 q1 = q0;
            UNPACK8(q0, q1, u)
            float d[8];
#pragma unroll
            for (int k = 0; k < 4; ++k) {
                d[2 * k]     = baseD[((size_t)(u[k] & 0xffffu) << 6) + h];
                d[2 * k + 1] = baseD[((size_t)(u[k] >> 16) << 6) + h];
            }
#pragma unroll
            for (int k = 0; k < 8; ++k) T1 += s2core(Apb + d[k]);
        }
        for (; c < mf; ++c) {
            unsigned jl = (unsigned)__builtin_amdgcn_readfirstlane((int)L[c]);
            T1 += s2core(Apb + baseD[((size_t)jl << 6) + h]);
        }
    }
    {   // rev stream: T2 += s2(Dpb + A_j)
        const unsigned short* L = sRev[w];
        int c = 0;
        for (; c + 16 <= mr; c += 16) {
            int4 q0 = *(const int4*)(L + c);
            int4 q1 = *(const int4*)(L + c + 8);
            UNPACK8(q0, q1, u)
            float d[16];
#pragma unroll
            for (int k = 0; k < 8; ++k) {
                d[2 * k]     = baseA[((size_t)(u[k] & 0xffffu) << 6) + h];
                d[2 * k + 1] = baseA[((size_t)(u[k] >> 16) << 6) + h];
            }
#pragma unroll
            for (int k = 0; k < 16; ++k) T2 += s2core(Dpb + d[k]);
        }
        for (; c + 8 <= mr; c += 8) {
            int4 q0 = *(const int4*)(L + c);
            int4 q1 = q0;
            UNPACK8(q0, q1, u)
            float d[8];
#pragma unroll
            for (int k = 0; k < 4; ++k) {
                d[2 * k]     = baseA[((size_t)(u[k] & 0xffffu) << 6) + h];
                d[2 * k + 1] = baseA[((size_t)(u[k] >> 16) << 6) + h];
            }
#pragma unroll
            for (int k = 0; k < 8; ++k) T2 += s2core(Dpb + d[k]);
        }
        for (; c < mr; ++c) {
            unsigned jl = (unsigned)__builtin_amdgcn_readfirstlane((int)L[c]);
            T2 += s2core(Dpb + baseA[((size_t)jl << 6) + h]);
        }
    }
#undef UNPACK8

    sS[w][h] = vh4 * T1;
    sS[w][64 + h] = vh4 * T2;
    __threadfence_block();                    // wave-local: no block barrier needed

    float g = 0.f;
    if (h < 32) {                             // l<16: W1_top@S1 ; 16<=l<32: W1_bot@S2
        const float* Sv = &sS[w][(h < 16) ? 0 : 64];
        float acc = 0.f;
        for (int hh = 0; hh < 64; hh++) acc = fmaf(sW1t[hh * 33 + h], Sv[hh], acc);
        g = acc;
    }
    float g2 = __shfl(g, (h + 16) & 63);
    if (h < DD) {
        float xn = x[(size_t)p * DD + h] - DT_C * (g + g2);
        xOut[(size_t)p * DD + h] = xn;
        if (h < 2) posOut[p * 2 + h] = xn;
    }
}

extern "C" void kernel_launch(void* const* d_in, const int* in_sizes, int n_in,
                              void* d_out, int out_size, void* d_ws, size_t ws_size,
                              hipStream_t stream) {
    const float* x0   = (const float*)d_in[0];
    const float* W1   = (const float*)d_in[1];
    const float* b1   = (const float*)d_in[2];
    const float* W2   = (const float*)d_in[3];
    const float* Wout = (const float*)d_in[5];
    float* out = (float*)d_out;

    // workspace layout (floats); total ~24 MB
    float* ws   = (float*)d_ws;
    float* posA = ws;                        // 32768 (dead sink for last step)
    float* posB = posA + 32768;              // 32768
    float* x1   = posB + 32768;              // 262144
    float* Apl  = x1 + 262144;               // 16384*64 (4 MB)
    float* Dpl  = Apl + 16384 * 64;          // 16384*64 (4 MB)
    float* cut  = Dpl + 16384 * 64;          // 16384
    int*   cnt  = (int*)(cut + 16384);       // 16384
    float2* cand = (float2*)(cnt + 16384);   // 16384*96 float2 (12.6 MB)
    unsigned short* fwd = (unsigned short*)(cand + (size_t)16384 * CAP);  // 16384*48
    float2* sPosS = (float2*)(fwd + (size_t)16384 * FCAP);                // 16384 float2
    unsigned short* sIdx = (unsigned short*)(sPosS + 16384);              // 16384
    int* bandStart = (int*)(sIdx + 16384);                                // 8*32

    const int NB = (BB * NN) / WPB;          // 2048 blocks x 512 thr

    // step 0: x0 -> x1
    k_bin<true><<<BB, 1024, 0, stream>>>(x0, nullptr, sPosS, sIdx, bandStart);
    k_neighbors<<<NB, BLOCK, 0, stream>>>(x0, sPosS, sIdx, bandStart, W1,
                                          cand, fwd, cnt, cut, Apl, Dpl);
    k_grad<<<NB, BLOCK, 0, stream>>>(x0, cut, cnt, cand, fwd, Apl, Dpl,
                                     W1, b1, W2, Wout, x1, posB);
    // step 1: x1 -> out
    k_bin<false><<<BB, 1024, 0, stream>>>(nullptr, posB, sPosS, sIdx, bandStart);
    k_neighbors<<<NB, BLOCK, 0, stream>>>(x1, sPosS, sIdx, bandStart, W1,
                                          cand, fwd, cnt, cut, Apl, Dpl);
    k_grad<<<NB, BLOCK, 0, stream>>>(x1, cut, cnt, cand, fwd, Apl, Dpl,
                                     W1, b1, W2, Wout, out, posA);
}